// Round 3
// baseline (214.986 us; speedup 1.0000x reference)
//
#include <hip/hip_runtime.h>
#include <hip/hip_fp16.h>
#include <math.h>

#define HH 1024
#define WW 1024
#define BB 16
#define ROWS 4
#define SROWS (ROWS + 2)
#define NID 32
#define NPX (1ull * BB * HH * WW)

// ws layout (floats): [0..6] partial sums
//   0: focal 1: inter 2: psum 3: tsum 4: loss_mag 5: dir_sum 6: mask_sum
// [16..528) seg_sum[B][32], [528..1040) seg_cnt[B][32]

__device__ __forceinline__ float fast_rcp(float x) {
  float r; asm("v_rcp_f32 %0, %1" : "=v"(r) : "v"(x)); return r;
}
__device__ __forceinline__ float fast_rsq(float x) {
  float r; asm("v_rsq_f32 %0, %1" : "=v"(r) : "v"(x)); return r;
}

__global__ __launch_bounds__(256, 6) void seg_main(
    const float* __restrict__ pred, const float* __restrict__ targ,
    const int* __restrict__ ids, float* __restrict__ acc,
    float* __restrict__ seg_sum, float* __restrict__ seg_cnt) {
  __shared__ __half ptile[SROWS][WW];   // fp16: feeds sobel only
  __shared__ __half ttile[SROWS][WW];   // t is {0,1} -> exact in fp16
  __shared__ float s_sum[NID];
  __shared__ float s_cnt[NID];
  __shared__ float red[4][8];

  const int tid = threadIdx.x;
  const int b  = blockIdx.x >> 8;
  const int rg = blockIdx.x & 255;
  const int h0 = rg * ROWS;
  const int w0 = tid * 4;

  if (tid < NID) { s_sum[tid] = 0.f; s_cnt[tid] = 0.f; }
  __syncthreads();

  const size_t base = (size_t)b * HH * WW;
  const float4* pb4 = (const float4*)(pred + base);
  const float4* tb4 = (const float4*)(targ + base);
  const int4*   ib4 = (const int4*)(ids + base);

  float facc = 0.f, iacc = 0.f, pacc = 0.f, tacc = 0.f;
  float macc = 0.f, dacc = 0.f, kacc = 0.f;

  // ---- staging: sigmoid+clip -> fp16 LDS; fused focal/dice/segment ----
  #pragma unroll
  for (int it = 0; it < SROWS; ++it) {
    int hh = h0 - 1 + it;
    hh = hh < 0 ? 0 : (hh > HH - 1 ? HH - 1 : hh);
    float4 xv = pb4[hh * (WW / 4) + tid];
    float4 tv = tb4[hh * (WW / 4) + tid];
    const bool interior = (it >= 1 && it <= ROWS);
    int ia[4];
    if (interior) {
      int4 iv = ib4[(h0 + it - 1) * (WW / 4) + tid];
      ia[0] = iv.x; ia[1] = iv.y; ia[2] = iv.z; ia[3] = iv.w;
    }
    float xa[4] = {xv.x, xv.y, xv.z, xv.w};
    float ta[4] = {tv.x, tv.y, tv.z, tv.w};
    float pa[4];
    #pragma unroll
    for (int j = 0; j < 4; ++j) {
      float x = xa[j];
      float e = __expf(-x);
      float p = fast_rcp(1.f + e);
      p = fminf(fmaxf(p, 1e-6f), 1.f - 1e-6f);
      pa[j] = p;
      float t = fminf(fmaxf(ta[j], 0.f), 1.f);
      ta[j] = t;
      if (interior) {
        // log(sigmoid) identities, clamped to the clip range
        float L  = __logf(1.f + e);
        float lp = fminf(fmaxf(-L,     -13.815511f), -1.0000005e-6f);
        float lq = fminf(fmaxf(-x - L, -13.815511f), -1.0000005e-6f);
        float bce = -(t * lp + (1.f - t) * lq);
        bool one = (t == 1.f);
        float ptv = one ? p : 1.f - p;
        float om  = 1.f - ptv;
        facc += (one ? 0.25f : 0.75f) * om * om * bce;
        iacc += p * t;
        pacc += p;
        tacc += t;
        atomicAdd(&s_sum[ia[j]], p);
        atomicAdd(&s_cnt[ia[j]], 1.f);
      }
    }
    *(__half2*)&ptile[it][w0]     = __floats2half2_rn(pa[0], pa[1]);
    *(__half2*)&ptile[it][w0 + 2] = __floats2half2_rn(pa[2], pa[3]);
    *(__half2*)&ttile[it][w0]     = __floats2half2_rn(ta[0], ta[1]);
    *(__half2*)&ttile[it][w0 + 2] = __floats2half2_rn(ta[2], ta[3]);
  }
  __syncthreads();

  // ---- sobel: rolling 3 rows in registers, fp16 LDS reads ----
  float P[3][6], T[3][6];
  #define LOADROW(tr, dst)                                                   \
    do {                                                                     \
      __half2 a0 = *(const __half2*)&ptile[(tr)][w0];                        \
      __half2 a1 = *(const __half2*)&ptile[(tr)][w0 + 2];                    \
      P[dst][1] = __low2float(a0);  P[dst][2] = __high2float(a0);            \
      P[dst][3] = __low2float(a1);  P[dst][4] = __high2float(a1);            \
      P[dst][0] = __half2float(ptile[(tr)][w0 == 0 ? 0 : w0 - 1]);           \
      P[dst][5] = __half2float(ptile[(tr)][w0 == WW - 4 ? WW - 1 : w0 + 4]); \
      __half2 b0 = *(const __half2*)&ttile[(tr)][w0];                        \
      __half2 b1 = *(const __half2*)&ttile[(tr)][w0 + 2];                    \
      T[dst][1] = __low2float(b0);  T[dst][2] = __high2float(b0);            \
      T[dst][3] = __low2float(b1);  T[dst][4] = __high2float(b1);            \
      T[dst][0] = __half2float(ttile[(tr)][w0 == 0 ? 0 : w0 - 1]);           \
      T[dst][5] = __half2float(ttile[(tr)][w0 == WW - 4 ? WW - 1 : w0 + 4]); \
    } while (0)

  LOADROW(0, 0);
  LOADROW(1, 1);
  #pragma unroll
  for (int r = 0; r < ROWS; ++r) {
    const int iA = r % 3, iB = (r + 1) % 3, iC = (r + 2) % 3;
    LOADROW(r + 2, iC);
    #pragma unroll
    for (int j = 0; j < 4; ++j) {
      float t00 = T[iA][j], t01 = T[iA][j + 1], t02 = T[iA][j + 2];
      float t10 = T[iB][j],                     t12 = T[iB][j + 2];
      float t20 = T[iC][j], t21 = T[iC][j + 1], t22 = T[iC][j + 2];
      float tgx = (t02 - t00 + 2.f * (t12 - t10) + t22 - t20) * 0.125f;
      float tgy = (t20 - t00 + 2.f * (t21 - t01) + t22 - t02) * 0.125f;
      float p00 = P[iA][j], p01 = P[iA][j + 1], p02 = P[iA][j + 2];
      float p10 = P[iB][j],                     p12 = P[iB][j + 2];
      float p20 = P[iC][j], p21 = P[iC][j + 1], p22 = P[iC][j + 2];
      float pgx = (p02 - p00 + 2.f * (p12 - p10) + p22 - p20) * 0.125f;
      float pgy = (p20 - p00 + 2.f * (p21 - p01) + p22 - p02) * 0.125f;

      float m2t = tgx * tgx + tgy * tgy + 1e-6f;
      float rst = fast_rsq(m2t);
      float tmag = m2t * rst;
      float m2p = pgx * pgx + pgy * pgy + 1e-6f;
      float rsp = fast_rsq(m2p);
      float pmag = m2p * rsp;

      float bwv = 1.f + 5.f * tmag;
      float d = (pmag - tmag) * bwv;
      macc += d * d;
      if (tmag > 0.1f) {
        float cosv = (tgx * pgx + tgy * pgy) * (rst * rsp);
        dacc += 1.f - cosv;
        kacc += 1.f;
      }
    }
  }
  #undef LOADROW

  // ---- block reduce 7 accumulators ----
  float v[7] = {facc, iacc, pacc, tacc, macc, dacc, kacc};
  #pragma unroll
  for (int j = 0; j < 7; ++j) {
    float x = v[j];
    #pragma unroll
    for (int off = 32; off > 0; off >>= 1) x += __shfl_down(x, off, 64);
    v[j] = x;
  }
  int wave = tid >> 6;
  int lane = tid & 63;
  if (lane == 0) {
    #pragma unroll
    for (int j = 0; j < 7; ++j) red[wave][j] = v[j];
  }
  __syncthreads();
  if (tid < 7) {
    float s = red[0][tid] + red[1][tid] + red[2][tid] + red[3][tid];
    atomicAdd(&acc[tid], s);
  }
  if (tid < NID) {
    atomicAdd(&seg_sum[b * NID + tid], s_sum[tid]);
    atomicAdd(&seg_cnt[b * NID + tid], s_cnt[tid]);
  }
}

__global__ void seg_final(const float* __restrict__ acc,
                          const float* __restrict__ seg_sum,
                          const float* __restrict__ seg_cnt,
                          float* __restrict__ out) {
  __shared__ float contr[BB];
  int tid = threadIdx.x;              // 256 threads
  int b   = tid >> 4;                 // 16 threads per image
  int l16 = tid & 15;
  if (b < BB) {
    float means[NID];
    bool  val[NID];
    #pragma unroll
    for (int k = 0; k < NID; ++k) {
      float c = seg_cnt[b * NID + k];
      means[k] = seg_sum[b * NID + k] / fmaxf(c, 1.f);
      val[k] = (c > 0.f) && (k > 0);
    }
    float csum = 0.f, np = 0.f;
    int cnt = 0;
    #pragma unroll
    for (int k = 0; k < NID; ++k) {
      #pragma unroll
      for (int l = k + 1; l < NID; ++l) {
        if ((cnt & 15) == l16) {
          if (val[k] && val[l]) {
            csum += __expf(-fabsf(means[k] - means[l]));
            np += 1.f;
          }
        }
        ++cnt;
      }
    }
    #pragma unroll
    for (int off = 1; off < 16; off <<= 1) {
      csum += __shfl_xor(csum, off, 16);
      np   += __shfl_xor(np,   off, 16);
    }
    if (l16 == 0) contr[b] = (np > 0.f) ? csum / fmaxf(np, 1.f) : 0.f;
  }
  __syncthreads();
  if (tid == 0) {
    float c = 0.f;
    for (int b2 = 0; b2 < BB; ++b2) c += contr[b2];
    c /= (float)BB;
    float N = (float)NPX;
    float focal = acc[0] / N;
    float dice  = 1.f - (2.f * acc[1] + 1e-6f) / (acc[2] + acc[3] + 1e-6f);
    float dir   = (acc[6] > 0.f) ? acc[5] / fmaxf(acc[6], 1.f) : 0.f;
    float boundary = acc[4] / N + dir;
    out[0] = focal + dice + 0.5f * boundary + 0.1f * c;
  }
}

extern "C" void kernel_launch(void* const* d_in, const int* in_sizes, int n_in,
                              void* d_out, int out_size, void* d_ws, size_t ws_size,
                              hipStream_t stream) {
  const float* pred = (const float*)d_in[0];
  const float* targ = (const float*)d_in[1];
  const int*   ids  = (const int*)d_in[2];
  float* ws = (float*)d_ws;
  float* acc     = ws;
  float* seg_sum = ws + 16;
  float* seg_cnt = ws + 16 + BB * NID;

  hipMemsetAsync(d_ws, 0, (16 + 2 * BB * NID) * sizeof(float), stream);

  int blocks = BB * (HH / ROWS);   // 4096
  seg_main<<<blocks, 256, 0, stream>>>(pred, targ, ids, acc, seg_sum, seg_cnt);
  seg_final<<<1, 256, 0, stream>>>(acc, seg_sum, seg_cnt, (float*)d_out);
}

// Round 4
// 139.012 us; speedup vs baseline: 1.5465x; 1.5465x over previous
//
#include <hip/hip_runtime.h>
#include <math.h>

#define HH 1024
#define WW 1024
#define BB 16
#define RR 16                    // rows per block strip
#define NID 32
#define NPX (1ull * BB * HH * WW)
#define CBIT 41                  // count lives in bits [41,64)
#define SSCALE 262144.0f         // 2^18 fixed point for p
#define INV_SSCALE 3.814697265625e-06f

// ws layout: [0..16) floats: acc (7 used)
//            byte offset 64: seg_pack[B][32] (u64)

__device__ __forceinline__ float fast_rcp(float x) {
  float r; asm("v_rcp_f32 %0, %1" : "=v"(r) : "v"(x)); return r;
}
__device__ __forceinline__ float fast_rsq(float x) {
  float r; asm("v_rsq_f32 %0, %1" : "=v"(r) : "v"(x)); return r;
}

__global__ __launch_bounds__(256, 4) void seg_main(
    const float* __restrict__ pred, const float* __restrict__ targ,
    const int* __restrict__ ids, float* __restrict__ acc,
    unsigned long long* __restrict__ seg_pack) {
  __shared__ unsigned long long s_pack[NID];
  __shared__ float red[4][8];

  const int tid = threadIdx.x;
  const int b  = blockIdx.x >> 6;      // 64 strips per image
  const int rg = blockIdx.x & 63;
  const int h0 = rg * RR;
  const int w0 = tid * 4;
  const int wl = (w0 == 0) ? 0 : w0 - 1;
  const int wr = (w0 == WW - 4) ? WW - 1 : w0 + 4;

  if (tid < NID) s_pack[tid] = 0ull;
  __syncthreads();

  const size_t base = (size_t)b * HH * WW;
  const float*  pb  = pred + base;
  const float*  tb  = targ + base;
  const float4* pb4 = (const float4*)pb;
  const float4* tb4 = (const float4*)tb;
  const int4*   ib4 = (const int4*)(ids + base);

  float facc = 0.f, iacc = 0.f, pacc = 0.f, tacc = 0.f;
  float macc = 0.f, dacc = 0.f, kacc = 0.f;

  float P[3][6], T[3][6];
  float4 rxA, rtA, rxB, rtB;
  float rxlA, rxrA, rtlA, rtrA, rxlB, rxrB, rtlB, rtrB;
  int4 idv, idn;

#define LOADRAW(h, S)                                                 \
  do { int hh = (h); hh = hh < 0 ? 0 : (hh > HH - 1 ? HH - 1 : hh);   \
    rx##S  = pb4[hh * (WW / 4) + tid];                                \
    rxl##S = pb[hh * WW + wl];  rxr##S = pb[hh * WW + wr];            \
    rt##S  = tb4[hh * (WW / 4) + tid];                                \
    rtl##S = tb[hh * WW + wl];  rtr##S = tb[hh * WW + wr];            \
  } while (0)

#define SIGROW(s, S)                                                         \
  do {                                                                       \
    float xa[6] = {rxl##S, rx##S.x, rx##S.y, rx##S.z, rx##S.w, rxr##S};      \
    float ta[6] = {rtl##S, rt##S.x, rt##S.y, rt##S.z, rt##S.w, rtr##S};      \
    _Pragma("unroll")                                                        \
    for (int j = 0; j < 6; ++j) {                                            \
      float p = fast_rcp(1.f + __expf(-xa[j]));                              \
      P[s][j] = fminf(fmaxf(p, 1e-6f), 1.f - 1e-6f);                         \
      T[s][j] = fminf(fmaxf(ta[j], 0.f), 1.f);                               \
    }                                                                        \
  } while (0)

  // prologue: overlap the two halo-row loads, then pipeline one row ahead
  LOADRAW(h0 - 1, A);
  LOADRAW(h0,     B);
  idv = ib4[h0 * (WW / 4) + tid];
  SIGROW(0, A);
  SIGROW(1, B);
  LOADRAW(h0 + 1, A);           // pending raw for iter 0 (consumes A)

  #pragma unroll
  for (int r = 0; r < RR; ++r) {
    const int iT = r % 3, iC = (r + 1) % 3, iB = (r + 2) % 3;

    // issue next-next loads into the opposite raw buffer (covered by compute)
    if (r < RR - 1) {
      if (r & 1) { LOADRAW(h0 + r + 2, A); }
      else       { LOADRAW(h0 + r + 2, B); }
      idn = ib4[(h0 + r + 1) * (WW / 4) + tid];
    }

    // sigmoid the pending raw (row h0+r+1) into the bottom slot
    if (r & 1) { SIGROW(iB, B); } else { SIGROW(iB, A); }

    #pragma unroll
    for (int j = 0; j < 4; ++j) {
      float p = P[iC][j + 1];
      float t = T[iC][j + 1];
      // focal (t is exactly 0 or 1)
      bool one = (t == 1.f);
      float pt = one ? p : 1.f - p;
      float om = 1.f - pt;
      facc += (one ? 0.25f : 0.75f) * om * om * (-__logf(pt));
      // dice partials
      iacc += p * t;
      pacc += p;
      tacc += t;
      // sobel
      float t00 = T[iT][j], t01 = T[iT][j + 1], t02 = T[iT][j + 2];
      float t10 = T[iC][j],                     t12 = T[iC][j + 2];
      float t20 = T[iB][j], t21 = T[iB][j + 1], t22 = T[iB][j + 2];
      float tgx = (t02 - t00 + 2.f * (t12 - t10) + t22 - t20) * 0.125f;
      float tgy = (t20 - t00 + 2.f * (t21 - t01) + t22 - t02) * 0.125f;
      float p00 = P[iT][j], p01 = P[iT][j + 1], p02 = P[iT][j + 2];
      float p10 = P[iC][j],                     p12 = P[iC][j + 2];
      float p20 = P[iB][j], p21 = P[iB][j + 1], p22 = P[iB][j + 2];
      float pgx = (p02 - p00 + 2.f * (p12 - p10) + p22 - p20) * 0.125f;
      float pgy = (p20 - p00 + 2.f * (p21 - p01) + p22 - p02) * 0.125f;
      float m2t = tgx * tgx + tgy * tgy + 1e-6f;
      float rst = fast_rsq(m2t);
      float tmag = m2t * rst;
      float m2p = pgx * pgx + pgy * pgy + 1e-6f;
      float rsp = fast_rsq(m2p);
      float pmag = m2p * rsp;
      float bwv = 1.f + 5.f * tmag;
      float d = (pmag - tmag) * bwv;
      macc += d * d;
      if (tmag > 0.1f) {
        dacc += 1.f - (tgx * pgx + tgy * pgy) * (rst * rsp);
        kacc += 1.f;
      }
      // segment partial: one packed u64 atomic per pixel
      int id = (j == 0) ? idv.x : (j == 1) ? idv.y : (j == 2) ? idv.z : idv.w;
      unsigned int q = __float2uint_rn(p * SSCALE);
      atomicAdd(&s_pack[id], (1ull << CBIT) | (unsigned long long)q);
    }
    if (r < RR - 1) idv = idn;
  }

  // block reduce 7 accumulators (once per block)
  float v[7] = {facc, iacc, pacc, tacc, macc, dacc, kacc};
  #pragma unroll
  for (int jq = 0; jq < 7; ++jq) {
    float x = v[jq];
    #pragma unroll
    for (int off = 32; off > 0; off >>= 1) x += __shfl_down(x, off, 64);
    v[jq] = x;
  }
  int wave = tid >> 6, lane = tid & 63;
  if (lane == 0) {
    #pragma unroll
    for (int jq = 0; jq < 7; ++jq) red[wave][jq] = v[jq];
  }
  __syncthreads();
  if (tid < 7) {
    atomicAdd(&acc[tid], red[0][tid] + red[1][tid] + red[2][tid] + red[3][tid]);
  }
  if (tid < NID) {
    atomicAdd(&seg_pack[b * NID + tid], s_pack[tid]);
  }
#undef LOADRAW
#undef SIGROW
}

__global__ void seg_final(const float* __restrict__ acc,
                          const unsigned long long* __restrict__ seg_pack,
                          float* __restrict__ out) {
  __shared__ float contr[BB];
  int tid = threadIdx.x;              // 256 threads
  int b   = tid >> 4;                 // 16 threads per image
  int l16 = tid & 15;
  if (b < BB) {
    float means[NID];
    bool  val[NID];
    #pragma unroll
    for (int k = 0; k < NID; ++k) {
      unsigned long long v = seg_pack[b * NID + k];
      float cnt = (float)(v >> CBIT);
      float sum = (float)(v & ((1ull << CBIT) - 1)) * INV_SSCALE;
      means[k] = sum / fmaxf(cnt, 1.f);
      val[k] = (cnt > 0.f) && (k > 0);
    }
    float csum = 0.f, np = 0.f;
    int cnt = 0;
    #pragma unroll
    for (int k = 0; k < NID; ++k) {
      #pragma unroll
      for (int l = k + 1; l < NID; ++l) {
        if ((cnt & 15) == l16) {
          if (val[k] && val[l]) {
            csum += __expf(-fabsf(means[k] - means[l]));
            np += 1.f;
          }
        }
        ++cnt;
      }
    }
    #pragma unroll
    for (int off = 1; off < 16; off <<= 1) {
      csum += __shfl_xor(csum, off, 16);
      np   += __shfl_xor(np,   off, 16);
    }
    if (l16 == 0) contr[b] = (np > 0.f) ? csum / fmaxf(np, 1.f) : 0.f;
  }
  __syncthreads();
  if (tid == 0) {
    float c = 0.f;
    for (int b2 = 0; b2 < BB; ++b2) c += contr[b2];
    c /= (float)BB;
    float N = (float)NPX;
    float focal = acc[0] / N;
    float dice  = 1.f - (2.f * acc[1] + 1e-6f) / (acc[2] + acc[3] + 1e-6f);
    float dir   = (acc[6] > 0.f) ? acc[5] / fmaxf(acc[6], 1.f) : 0.f;
    float boundary = acc[4] / N + dir;
    out[0] = focal + dice + 0.5f * boundary + 0.1f * c;
  }
}

extern "C" void kernel_launch(void* const* d_in, const int* in_sizes, int n_in,
                              void* d_out, int out_size, void* d_ws, size_t ws_size,
                              hipStream_t stream) {
  const float* pred = (const float*)d_in[0];
  const float* targ = (const float*)d_in[1];
  const int*   ids  = (const int*)d_in[2];
  float* acc = (float*)d_ws;
  unsigned long long* seg_pack = (unsigned long long*)((char*)d_ws + 64);

  hipMemsetAsync(d_ws, 0, 64 + BB * NID * sizeof(unsigned long long), stream);

  int blocks = BB * (HH / RR);   // 1024
  seg_main<<<blocks, 256, 0, stream>>>(pred, targ, ids, acc, seg_pack);
  seg_final<<<1, 256, 0, stream>>>(acc, seg_pack, (float*)d_out);
}

// Round 5
// 115.871 us; speedup vs baseline: 1.8554x; 1.1997x over previous
//
#include <hip/hip_runtime.h>
#include <math.h>

#define HH 1024
#define WW 1024
#define BB 16
#define RR 16                    // rows per block strip
#define NID 32
#define NPX (1ull * BB * HH * WW)
#define CBIT 41                  // count lives in bits [41,64)
#define SSCALE 262144.0f         // 2^18 fixed point for p
#define INV_SSCALE 3.814697265625e-06f

// ws layout: [0..16) floats: acc (7 used)
//            byte offset 64: seg_pack[B][32] (u64)

__device__ __forceinline__ float fast_rcp(float x) {
  float r; asm("v_rcp_f32 %0, %1" : "=v"(r) : "v"(x)); return r;
}
__device__ __forceinline__ float fast_rsq(float x) {
  float r; asm("v_rsq_f32 %0, %1" : "=v"(r) : "v"(x)); return r;
}

__global__ __launch_bounds__(256, 4) void seg_main(
    const float* __restrict__ pred, const float* __restrict__ targ,
    const int* __restrict__ ids, float* __restrict__ acc,
    unsigned long long* __restrict__ seg_pack) {
  __shared__ unsigned long long s_pack[NID];
  __shared__ float red[4][8];

  const int tid = threadIdx.x;
  const int b  = blockIdx.x >> 6;      // 64 strips per image
  const int rg = blockIdx.x & 63;
  const int h0 = rg * RR;
  const int w0 = tid * 4;
  const int wl = (w0 == 0) ? 0 : w0 - 1;
  const int wr = (w0 == WW - 4) ? WW - 1 : w0 + 4;

  if (tid < NID) s_pack[tid] = 0ull;
  __syncthreads();

  const size_t base = (size_t)b * HH * WW;
  const float*  pb  = pred + base;
  const float*  tb  = targ + base;
  const float4* pb4 = (const float4*)pb;
  const float4* tb4 = (const float4*)tb;
  const int4*   ib4 = (const int4*)(ids + base);

  float facc = 0.f, iacc = 0.f, pacc = 0.f, tacc = 0.f;
  float macc = 0.f, dacc = 0.f, kacc = 0.f;

  // static named row buffers (no rolling indices anywhere)
  float P0[6], P1[6], P2[6], T0[6], T1[6], T2[6];
  float4 nx, nt;                 // raw prefetch buffer (one row ahead)
  float nxl, nxr, ntl, ntr;
  int4 idv;

#define LOADRAW(h)                                                     \
  do { int hh = (h); hh = hh < 0 ? 0 : (hh > HH - 1 ? HH - 1 : hh);    \
    nx  = pb4[hh * (WW / 4) + tid];                                    \
    nxl = pb[hh * WW + wl];  nxr = pb[hh * WW + wr];                   \
    nt  = tb4[hh * (WW / 4) + tid];                                    \
    ntl = tb[hh * WW + wl];  ntr = tb[hh * WW + wr];                   \
  } while (0)

#define SIG(PD, TD)                                                    \
  do {                                                                 \
    float xa[6] = {nxl, nx.x, nx.y, nx.z, nx.w, nxr};                  \
    float ta[6] = {ntl, nt.x, nt.y, nt.z, nt.w, ntr};                  \
    _Pragma("unroll")                                                  \
    for (int j = 0; j < 6; ++j) {                                      \
      float p = fast_rcp(1.f + __expf(-xa[j]));                        \
      PD[j] = fminf(fmaxf(p, 1e-6f), 1.f - 1e-6f);                     \
      TD[j] = fminf(fmaxf(ta[j], 0.f), 1.f);                           \
    }                                                                  \
  } while (0)

// BODY r: PA/TA = row r-1 (top), PB/TB = row r (center), raw holds row r+1.
#define BODY(PA, PB, PC, TA, TB, TC, r)                                \
  do {                                                                 \
    idv = ib4[(h0 + (r)) * (WW / 4) + tid];                            \
    SIG(PC, TC);                          /* row r+1 -> bottom */      \
    if ((r) < RR - 1) LOADRAW(h0 + (r) + 2);                           \
    _Pragma("unroll")                                                  \
    for (int j = 0; j < 4; ++j) {                                      \
      float p = PB[j + 1];                                             \
      float t = TB[j + 1];                                             \
      bool one = (t == 1.f);                                           \
      float pt = one ? p : 1.f - p;                                    \
      float om = 1.f - pt;                                             \
      facc += (one ? 0.25f : 0.75f) * om * om * (-__logf(pt));         \
      iacc += p * t;                                                   \
      pacc += p;                                                       \
      tacc += t;                                                       \
      float t00 = TA[j], t01 = TA[j + 1], t02 = TA[j + 2];             \
      float t10 = TB[j],                  t12 = TB[j + 2];             \
      float t20 = TC[j], t21 = TC[j + 1], t22 = TC[j + 2];             \
      float tgx = (t02 - t00 + 2.f * (t12 - t10) + t22 - t20) * 0.125f;\
      float tgy = (t20 - t00 + 2.f * (t21 - t01) + t22 - t02) * 0.125f;\
      float p00 = PA[j], p01 = PA[j + 1], p02 = PA[j + 2];             \
      float p10 = PB[j],                  p12 = PB[j + 2];             \
      float p20 = PC[j], p21 = PC[j + 1], p22 = PC[j + 2];             \
      float pgx = (p02 - p00 + 2.f * (p12 - p10) + p22 - p20) * 0.125f;\
      float pgy = (p20 - p00 + 2.f * (p21 - p01) + p22 - p02) * 0.125f;\
      float m2t = tgx * tgx + tgy * tgy + 1e-6f;                       \
      float rst = fast_rsq(m2t);                                       \
      float tmag = m2t * rst;                                          \
      float m2p = pgx * pgx + pgy * pgy + 1e-6f;                       \
      float rsp = fast_rsq(m2p);                                       \
      float pmag = m2p * rsp;                                          \
      float bwv = 1.f + 5.f * tmag;                                    \
      float d = (pmag - tmag) * bwv;                                   \
      macc += d * d;                                                   \
      if (tmag > 0.1f) {                                               \
        dacc += 1.f - (tgx * pgx + tgy * pgy) * (rst * rsp);           \
        kacc += 1.f;                                                   \
      }                                                                \
      int id = (j == 0) ? idv.x : (j == 1) ? idv.y                     \
             : (j == 2) ? idv.z : idv.w;                               \
      unsigned int q = __float2uint_rn(p * SSCALE);                    \
      atomicAdd(&s_pack[id], (1ull << CBIT) | (unsigned long long)q);  \
    }                                                                  \
  } while (0)

  // prologue
  LOADRAW(h0 - 1); SIG(P0, T0);
  LOADRAW(h0);     SIG(P1, T1);
  LOADRAW(h0 + 1);                 // pending raw for BODY 0

  // 16 explicit bodies, buffer names rotate with period 3
  BODY(P0, P1, P2, T0, T1, T2, 0);
  BODY(P1, P2, P0, T1, T2, T0, 1);
  BODY(P2, P0, P1, T2, T0, T1, 2);
  BODY(P0, P1, P2, T0, T1, T2, 3);
  BODY(P1, P2, P0, T1, T2, T0, 4);
  BODY(P2, P0, P1, T2, T0, T1, 5);
  BODY(P0, P1, P2, T0, T1, T2, 6);
  BODY(P1, P2, P0, T1, T2, T0, 7);
  BODY(P2, P0, P1, T2, T0, T1, 8);
  BODY(P0, P1, P2, T0, T1, T2, 9);
  BODY(P1, P2, P0, T1, T2, T0, 10);
  BODY(P2, P0, P1, T2, T0, T1, 11);
  BODY(P0, P1, P2, T0, T1, T2, 12);
  BODY(P1, P2, P0, T1, T2, T0, 13);
  BODY(P2, P0, P1, T2, T0, T1, 14);
  BODY(P0, P1, P2, T0, T1, T2, 15);

#undef LOADRAW
#undef SIG
#undef BODY

  // block reduce 7 accumulators (once per block)
  float v[7] = {facc, iacc, pacc, tacc, macc, dacc, kacc};
  #pragma unroll
  for (int jq = 0; jq < 7; ++jq) {
    float x = v[jq];
    #pragma unroll
    for (int off = 32; off > 0; off >>= 1) x += __shfl_down(x, off, 64);
    v[jq] = x;
  }
  int wave = tid >> 6, lane = tid & 63;
  if (lane == 0) {
    #pragma unroll
    for (int jq = 0; jq < 7; ++jq) red[wave][jq] = v[jq];
  }
  __syncthreads();
  if (tid < 7) {
    atomicAdd(&acc[tid], red[0][tid] + red[1][tid] + red[2][tid] + red[3][tid]);
  }
  if (tid < NID) {
    atomicAdd(&seg_pack[b * NID + tid], s_pack[tid]);
  }
}

__global__ void seg_final(const float* __restrict__ acc,
                          const unsigned long long* __restrict__ seg_pack,
                          float* __restrict__ out) {
  __shared__ float contr[BB];
  int tid = threadIdx.x;              // 256 threads
  int b   = tid >> 4;                 // 16 threads per image
  int l16 = tid & 15;
  if (b < BB) {
    float means[NID];
    bool  val[NID];
    #pragma unroll
    for (int k = 0; k < NID; ++k) {
      unsigned long long v = seg_pack[b * NID + k];
      float cnt = (float)(v >> CBIT);
      float sum = (float)(v & ((1ull << CBIT) - 1)) * INV_SSCALE;
      means[k] = sum / fmaxf(cnt, 1.f);
      val[k] = (cnt > 0.f) && (k > 0);
    }
    float csum = 0.f, np = 0.f;
    int cnt = 0;
    #pragma unroll
    for (int k = 0; k < NID; ++k) {
      #pragma unroll
      for (int l = k + 1; l < NID; ++l) {
        if ((cnt & 15) == l16) {
          if (val[k] && val[l]) {
            csum += __expf(-fabsf(means[k] - means[l]));
            np += 1.f;
          }
        }
        ++cnt;
      }
    }
    #pragma unroll
    for (int off = 1; off < 16; off <<= 1) {
      csum += __shfl_xor(csum, off, 16);
      np   += __shfl_xor(np,   off, 16);
    }
    if (l16 == 0) contr[b] = (np > 0.f) ? csum / fmaxf(np, 1.f) : 0.f;
  }
  __syncthreads();
  if (tid == 0) {
    float c = 0.f;
    for (int b2 = 0; b2 < BB; ++b2) c += contr[b2];
    c /= (float)BB;
    float N = (float)NPX;
    float focal = acc[0] / N;
    float dice  = 1.f - (2.f * acc[1] + 1e-6f) / (acc[2] + acc[3] + 1e-6f);
    float dir   = (acc[6] > 0.f) ? acc[5] / fmaxf(acc[6], 1.f) : 0.f;
    float boundary = acc[4] / N + dir;
    out[0] = focal + dice + 0.5f * boundary + 0.1f * c;
  }
}

extern "C" void kernel_launch(void* const* d_in, const int* in_sizes, int n_in,
                              void* d_out, int out_size, void* d_ws, size_t ws_size,
                              hipStream_t stream) {
  const float* pred = (const float*)d_in[0];
  const float* targ = (const float*)d_in[1];
  const int*   ids  = (const int*)d_in[2];
  float* acc = (float*)d_ws;
  unsigned long long* seg_pack = (unsigned long long*)((char*)d_ws + 64);

  hipMemsetAsync(d_ws, 0, 64 + BB * NID * sizeof(unsigned long long), stream);

  int blocks = BB * (HH / RR);   // 1024
  seg_main<<<blocks, 256, 0, stream>>>(pred, targ, ids, acc, seg_pack);
  seg_final<<<1, 256, 0, stream>>>(acc, seg_pack, (float*)d_out);
}